// Round 4
// baseline (330.709 us; speedup 1.0000x reference)
//
#include <hip/hip_runtime.h>
#include <cstdint>

#define TTOK 16384
#define HD   1024
#define NE   8
#define NDE  128
#define NDS  512
#define NC1  1536   // concat fc1 rows: E*DE routed + DS shared
#define KC2  1536   // concat fc2 cols in W2cat
#define NPAIR 28
#define MAXT  160   // max M-tiles over pair segments (<=128+27, padded to 8*20)
#define PREPB 3080
#define GATEB 4096
#define NH    768   // grouped hidden: 128(e1)+128(e2)+512(shared)

typedef float  f32x4  __attribute__((ext_vector_type(4)));
typedef __bf16 bf16x8 __attribute__((ext_vector_type(8)));

__device__ __forceinline__ unsigned short f2bf(float f) {
  unsigned int u = __float_as_uint(f);
  u += 0x7fffu + ((u >> 16) & 1u);   // RNE; inputs finite
  return (unsigned short)(u >> 16);
}

__device__ __forceinline__ void gl2lds16(const void* gp, void* lp) {
  void* g0 = const_cast<void*>(gp);
  __builtin_amdgcn_global_load_lds((__attribute__((address_space(1))) void*)g0,
                                   (__attribute__((address_space(3))) void*)lp,
                                   16, 0, 0);
}

// ---------------- K1: fused weight prep + gate (pair id, rank, weights, x->bf16) ----------------
__global__ __launch_bounds__(256) void prep_gate(
    const float* __restrict__ x, const float* __restrict__ Wg,
    const float* __restrict__ W1, const float* __restrict__ Ws1,
    const float* __restrict__ W2, const float* __restrict__ Ws2,
    const float* __restrict__ b1, const float* __restrict__ bs1,
    unsigned short* __restrict__ W1cat, unsigned short* __restrict__ W2cat,
    float* __restrict__ bias1, unsigned short* __restrict__ xbf,
    float2* __restrict__ wpair, int* __restrict__ prank, int* __restrict__ cnt) {
  if (blockIdx.x < PREPB) {
    const int total = NC1 * HD + HD * KC2 + NC1;
    for (int idx = blockIdx.x * 256 + threadIdx.x; idx < total; idx += PREPB * 256) {
      if (idx < NC1 * HD) {
        int r = idx >> 10, k = idx & 1023;
        float v = (r < 1024) ? W1[idx] : Ws1[(size_t)(r - 1024) * HD + k];
        W1cat[idx] = f2bf(v);
      } else if (idx < NC1 * HD + HD * KC2) {
        int i2 = idx - NC1 * HD;
        int h = i2 / KC2;
        int j = i2 - h * KC2;
        float v = (j < 1024) ? W2[(size_t)((j >> 7) * HD + h) * NDE + (j & 127)]
                             : Ws2[(size_t)h * NDS + (j - 1024)];
        W2cat[i2] = f2bf(v);
      } else {
        int r = idx - (NC1 * HD + HD * KC2);
        bias1[r] = (r < 1024) ? b1[r] : bs1[r - 1024];
      }
    }
    return;
  }
  // ---- gate ----
  const int lane = threadIdx.x & 63;
  const int wv   = threadIdx.x >> 6;
  const int t    = (blockIdx.x - PREPB) * 4 + wv;

  const float* xr = x + (size_t)t * HD + lane * 16;
  float4 x0 = ((const float4*)xr)[0];
  float4 x1 = ((const float4*)xr)[1];
  float4 x2 = ((const float4*)xr)[2];
  float4 x3 = ((const float4*)xr)[3];

  unsigned short* xo = xbf + (size_t)t * HD + lane * 16;
  union { unsigned short us[8]; uint4 v; } pk;
  pk.us[0] = f2bf(x0.x); pk.us[1] = f2bf(x0.y); pk.us[2] = f2bf(x0.z); pk.us[3] = f2bf(x0.w);
  pk.us[4] = f2bf(x1.x); pk.us[5] = f2bf(x1.y); pk.us[6] = f2bf(x1.z); pk.us[7] = f2bf(x1.w);
  ((uint4*)xo)[0] = pk.v;
  pk.us[0] = f2bf(x2.x); pk.us[1] = f2bf(x2.y); pk.us[2] = f2bf(x2.z); pk.us[3] = f2bf(x2.w);
  pk.us[4] = f2bf(x3.x); pk.us[5] = f2bf(x3.y); pk.us[6] = f2bf(x3.z); pk.us[7] = f2bf(x3.w);
  ((uint4*)xo)[1] = pk.v;

  float lg[8];
#pragma unroll
  for (int e = 0; e < 8; ++e) {
    const float4* wr = (const float4*)(Wg + (size_t)e * HD + lane * 16);
    float4 a = wr[0], b = wr[1], c = wr[2], d = wr[3];
    lg[e] = a.x * x0.x + a.y * x0.y + a.z * x0.z + a.w * x0.w +
            b.x * x1.x + b.y * x1.y + b.z * x1.z + b.w * x1.w +
            c.x * x2.x + c.y * x2.y + c.z * x2.z + c.w * x2.w +
            d.x * x3.x + d.y * x3.y + d.z * x3.z + d.w * x3.w;
  }
#pragma unroll
  for (int off = 32; off > 0; off >>= 1) {
#pragma unroll
    for (int e = 0; e < 8; ++e) lg[e] += __shfl_xor(lg[e], off, 64);
  }

  if (lane == 0) {
    int i1 = 0; float m1 = lg[0];
#pragma unroll
    for (int e = 1; e < 8; ++e) { if (lg[e] > m1) { m1 = lg[e]; i1 = e; } }
    int i2 = -1; float m2 = -3.4e38f;
#pragma unroll
    for (int e = 0; e < 8; ++e) { if (e != i1 && lg[e] > m2) { m2 = lg[e]; i2 = e; } }
    float Z = 0.f;
#pragma unroll
    for (int e = 0; e < 8; ++e) Z += expf(lg[e] - m1);
    float s1 = 1.f / Z;
    float s2 = expf(m2 - m1) / Z;
    float dn = s1 + s2 + 1e-20f;
    float w1 = s1 / dn, w2 = s2 / dn;
    int ef, es; float wf, wsx;
    if (i1 < i2) { ef = i1; es = i2; wf = w1; wsx = w2; }
    else         { ef = i2; es = i1; wf = w2; wsx = w1; }
    int p = ef * 7 - (ef * (ef - 1)) / 2 + (es - ef - 1);   // C(8,2) index, ef<es
    int rank = atomicAdd(&cnt[p], 1);
    wpair[t] = make_float2(wf, wsx);
    prank[t] = (p << 16) | rank;
  }
}

// ---------------- K2: scan counts, build perm + tile table ----------------
__global__ __launch_bounds__(256) void route_scan(const int* __restrict__ cnt,
                                                  const int* __restrict__ prank,
                                                  int* __restrict__ perm,
                                                  int4* __restrict__ tiletab,
                                                  int* __restrict__ ntct) {
  const int p = blockIdx.x;
  int c[NPAIR];
#pragma unroll
  for (int q = 0; q < NPAIR; ++q) c[q] = cnt[q];
  int estart = 0, tstart = 0;
  for (int q = 0; q < p; ++q) { estart += c[q]; tstart += (c[q] + 127) >> 7; }
  const int nt = (c[p] + 127) >> 7;
  if (p == NPAIR - 1 && threadIdx.x == 0) ntct[0] = tstart + nt;
  for (int k = threadIdx.x; k < nt; k += 256) {
    int4 e;
    e.x = p;
    e.y = estart + (k << 7);
    e.z = min(128, c[p] - (k << 7));
    e.w = (tstart + k) << 7;
    tiletab[tstart + k] = e;
  }
  for (int t = threadIdx.x; t < TTOK; t += 256) {
    int v = prank[t];
    if ((v >> 16) == p) perm[estart + (v & 0xffff)] = t;
  }
}

// ---------------- G1: grouped fc1: gather x rows, [128x768] per pair-tile ----------------
__global__ __launch_bounds__(256) void moe_fc1(const unsigned short* __restrict__ xbf,
                                               const unsigned short* __restrict__ W1cat,
                                               const int* __restrict__ perm,
                                               const float2* __restrict__ wpair,
                                               const float* __restrict__ bias1,
                                               const int4* __restrict__ tiletab,
                                               const int* __restrict__ ntct,
                                               unsigned short* __restrict__ Hbuf) {
  const int L   = blockIdx.x;
  const int xcd = L & 7;
  const int s   = L >> 3;
  const int mg  = s / 6;
  const int nn  = s - mg * 6;
  const int mt  = xcd + (mg << 3);
  if (mt >= ntct[0]) return;
  const int4 tt = tiletab[mt];
  const int eoff = tt.y, valid = tt.z, hbase = tt.w;
  int ef = 0, rem = tt.x;
  while (rem >= 7 - ef) { rem -= 7 - ef; ef++; }
  const int es = ef + 1 + rem;
  const int brow = (nn == 0) ? ef * 128 : (nn == 1) ? es * 128 : 1024 + ((nn - 2) << 7);

  __shared__ __align__(16) unsigned short As[128 * 64];
  __shared__ __align__(16) unsigned short Bs[128 * 64];

  const int tid  = threadIdx.x;
  const int lane = tid & 63;
  const int wv   = tid >> 6;
  const int wm   = wv >> 1;
  const int wn   = wv & 1;
  const int r16  = lane & 15;
  const int quad = lane >> 4;

  const unsigned short* gA[4];
  const unsigned short* gB[4];
  unsigned short* lA[4];
  unsigned short* lB[4];
#pragma unroll
  for (int i = 0; i < 4; ++i) {
    int idx = i * 256 + tid;
    int row = idx >> 3;
    int cc  = idx & 7;
    int kc  = cc ^ (row & 7);
    int tok = perm[eoff + min(row, valid - 1)];
    gA[i] = xbf + (size_t)tok * HD + kc * 8;
    gB[i] = W1cat + (size_t)(brow + row) * HD + kc * 8;
    lA[i] = As + idx * 8;
    lB[i] = Bs + idx * 8;
  }

  int aoff[4], boff[4];
#pragma unroll
  for (int i = 0; i < 4; ++i) {
    int ra = wm * 64 + i * 16 + r16;
    aoff[i] = ra * 64 + ((quad ^ (ra & 7)) << 3);
    int rb = wn * 64 + i * 16 + r16;
    boff[i] = rb * 64 + ((quad ^ (rb & 7)) << 3);
  }

  f32x4 acc[4][4];
#pragma unroll
  for (int i = 0; i < 4; ++i)
#pragma unroll
    for (int j = 0; j < 4; ++j) acc[i][j] = (f32x4){0.f, 0.f, 0.f, 0.f};

  for (int kt = 0; kt < 16; ++kt) {
    const int ko = kt << 6;
#pragma unroll
    for (int i = 0; i < 4; ++i) gl2lds16(gA[i] + ko, lA[i]);
#pragma unroll
    for (int i = 0; i < 4; ++i) gl2lds16(gB[i] + ko, lB[i]);
    __syncthreads();
#pragma unroll
    for (int g = 0; g < 2; ++g) {
      const int gx = g << 5;
      bf16x8 av[4], bv[4];
#pragma unroll
      for (int i = 0; i < 4; ++i) av[i] = *(const bf16x8*)(As + (aoff[i] ^ gx));
#pragma unroll
      for (int j = 0; j < 4; ++j) bv[j] = *(const bf16x8*)(Bs + (boff[j] ^ gx));
#pragma unroll
      for (int i = 0; i < 4; ++i)
#pragma unroll
        for (int j = 0; j < 4; ++j)
          acc[i][j] = __builtin_amdgcn_mfma_f32_16x16x32_bf16(av[i], bv[j], acc[i][j], 0, 0, 0);
    }
    __syncthreads();
  }

  // epilogue: relu(acc+b)*scale, scale = w1/w2/1 by nn
  float* wl = (float*)As;
  if (tid < 128) {
    int tok = perm[eoff + min(tid, valid - 1)];
    float sc = 1.0f;
    if (nn == 0) sc = wpair[tok].x;
    else if (nn == 1) sc = wpair[tok].y;
    wl[tid] = sc;
  }
  __syncthreads();
#pragma unroll
  for (int j = 0; j < 4; ++j) {
    const int cin = wn * 64 + j * 16 + r16;
    const float bz = bias1[brow + cin];
#pragma unroll
    for (int i = 0; i < 4; ++i) {
#pragma unroll
      for (int r = 0; r < 4; ++r) {
        const int lrow = wm * 64 + i * 16 + quad * 4 + r;
        float v = fmaxf(acc[i][j][r] + bz, 0.f) * wl[lrow];
        Hbuf[(size_t)(hbase + lrow) * NH + nn * 128 + cin] = f2bf(v);
      }
    }
  }
}

// ---------------- G2: grouped fc2: [128 tokens] x [128 h-cols], K=768, scatter out ----------------
__global__ __launch_bounds__(256) void moe_fc2(const unsigned short* __restrict__ Hbuf,
                                               const unsigned short* __restrict__ W2cat,
                                               const int* __restrict__ perm,
                                               const float2* __restrict__ wpair,
                                               const float* __restrict__ b2,
                                               const float* __restrict__ bs2,
                                               const int4* __restrict__ tiletab,
                                               const int* __restrict__ ntct,
                                               float* __restrict__ out) {
  const int L   = blockIdx.x;
  const int xcd = L & 7;
  const int s   = L >> 3;
  const int mg  = s >> 3;
  const int nn  = s & 7;
  const int mt  = xcd + (mg << 3);
  if (mt >= ntct[0]) return;
  const int4 tt = tiletab[mt];
  const int eoff = tt.y, valid = tt.z, hbase = tt.w;
  int ef = 0, rem = tt.x;
  while (rem >= 7 - ef) { rem -= 7 - ef; ef++; }
  const int es = ef + 1 + rem;
  const int tileN = nn << 7;

  __shared__ __align__(16) unsigned short As[128 * 64];
  __shared__ __align__(16) unsigned short Bs[128 * 64];

  const int tid  = threadIdx.x;
  const int lane = tid & 63;
  const int wv   = tid >> 6;
  const int wm   = wv >> 1;
  const int wn   = wv & 1;
  const int r16  = lane & 15;
  const int quad = lane >> 4;

  const unsigned short* gA[4];
  const unsigned short* gB[4];
  unsigned short* lA[4];
  unsigned short* lB[4];
#pragma unroll
  for (int i = 0; i < 4; ++i) {
    int idx = i * 256 + tid;
    int row = idx >> 3;
    int cc  = idx & 7;
    int kc  = cc ^ (row & 7);
    gA[i] = Hbuf + (size_t)(hbase + row) * NH + kc * 8;
    gB[i] = W2cat + (size_t)(tileN + row) * KC2 + kc * 8;
    lA[i] = As + idx * 8;
    lB[i] = Bs + idx * 8;
  }

  int aoff[4], boff[4];
#pragma unroll
  for (int i = 0; i < 4; ++i) {
    int ra = wm * 64 + i * 16 + r16;
    aoff[i] = ra * 64 + ((quad ^ (ra & 7)) << 3);
    int rb = wn * 64 + i * 16 + r16;
    boff[i] = rb * 64 + ((quad ^ (rb & 7)) << 3);
  }

  f32x4 acc[4][4];
#pragma unroll
  for (int i = 0; i < 4; ++i)
#pragma unroll
    for (int j = 0; j < 4; ++j) acc[i][j] = (f32x4){0.f, 0.f, 0.f, 0.f};

  for (int kt = 0; kt < 12; ++kt) {
    const int koA = kt << 6;
    const int koB = (kt < 2) ? ef * 128 + (kt << 6)
                 : (kt < 4) ? es * 128 + ((kt - 2) << 6)
                            : 1024 + ((kt - 4) << 6);
#pragma unroll
    for (int i = 0; i < 4; ++i) gl2lds16(gA[i] + koA, lA[i]);
#pragma unroll
    for (int i = 0; i < 4; ++i) gl2lds16(gB[i] + koB, lB[i]);
    __syncthreads();
#pragma unroll
    for (int g = 0; g < 2; ++g) {
      const int gx = g << 5;
      bf16x8 av[4], bv[4];
#pragma unroll
      for (int i = 0; i < 4; ++i) av[i] = *(const bf16x8*)(As + (aoff[i] ^ gx));
#pragma unroll
      for (int j = 0; j < 4; ++j) bv[j] = *(const bf16x8*)(Bs + (boff[j] ^ gx));
#pragma unroll
      for (int i = 0; i < 4; ++i)
#pragma unroll
        for (int j = 0; j < 4; ++j)
          acc[i][j] = __builtin_amdgcn_mfma_f32_16x16x32_bf16(av[i], bv[j], acc[i][j], 0, 0, 0);
    }
    __syncthreads();
  }

  // epilogue: + bs2 + w1*b2[e1] + w2*b2[e2], scatter to out[token]
  float2* wl2 = (float2*)As;
  int* tokl   = (int*)Bs;
  if (tid < 128) {
    int tokc = perm[eoff + min(tid, valid - 1)];
    tokl[tid] = (tid < valid) ? tokc : -1;
    wl2[tid] = wpair[tokc];
  }
  __syncthreads();
  float bsc[4], b2a[4], b2b[4];
#pragma unroll
  for (int j = 0; j < 4; ++j) {
    const int col = tileN + wn * 64 + j * 16 + r16;
    bsc[j] = bs2[col];
    b2a[j] = b2[(size_t)ef * HD + col];
    b2b[j] = b2[(size_t)es * HD + col];
  }
#pragma unroll
  for (int i = 0; i < 4; ++i) {
#pragma unroll
    for (int r = 0; r < 4; ++r) {
      const int lrow = wm * 64 + i * 16 + quad * 4 + r;
      const int tok = tokl[lrow];
      if (tok < 0) continue;
      const float2 w = wl2[lrow];
#pragma unroll
      for (int j = 0; j < 4; ++j) {
        const int col = tileN + wn * 64 + j * 16 + r16;
        out[(size_t)tok * HD + col] = acc[i][j][r] + bsc[j] + w.x * b2a[j] + w.y * b2b[j];
      }
    }
  }
}

extern "C" void kernel_launch(void* const* d_in, const int* in_sizes, int n_in,
                              void* d_out, int out_size, void* d_ws, size_t ws_size,
                              hipStream_t stream) {
  const float* x   = (const float*)d_in[0];
  const float* Wg  = (const float*)d_in[1];
  const float* W1  = (const float*)d_in[2];
  const float* b1  = (const float*)d_in[3];
  const float* W2  = (const float*)d_in[4];
  const float* b2  = (const float*)d_in[5];
  const float* Ws1 = (const float*)d_in[6];
  const float* bs1 = (const float*)d_in[7];
  const float* Ws2 = (const float*)d_in[8];
  const float* bs2 = (const float*)d_in[9];

  char* ws = (char*)d_ws;
  size_t off = 0;
  unsigned short* xbf   = (unsigned short*)(ws + off); off += (size_t)TTOK * HD * 2;       // 32 MiB
  unsigned short* Hbuf  = (unsigned short*)(ws + off); off += (size_t)MAXT * 128 * NH * 2; // 30 MiB
  unsigned short* W1cat = (unsigned short*)(ws + off); off += (size_t)NC1 * HD * 2;
  unsigned short* W2cat = (unsigned short*)(ws + off); off += (size_t)HD * KC2 * 2;
  float* bias1          = (float*)(ws + off);          off += (size_t)NC1 * 4;
  float2* wpair         = (float2*)(ws + off);         off += (size_t)TTOK * 8;
  int* prank            = (int*)(ws + off);            off += (size_t)TTOK * 4;
  int* perm             = (int*)(ws + off);            off += (size_t)TTOK * 4;
  int4* tiletab         = (int4*)(ws + off);           off += (size_t)MAXT * 16;
  int* cnt              = (int*)(ws + off);            off += 128;
  int* ntct             = (int*)(ws + off);            off += 16;

  hipMemsetAsync(cnt, 0, 128, stream);
  prep_gate<<<PREPB + GATEB, 256, 0, stream>>>(x, Wg, W1, Ws1, W2, Ws2, b1, bs1,
                                               W1cat, W2cat, bias1, xbf, wpair, prank, cnt);
  route_scan<<<NPAIR, 256, 0, stream>>>(cnt, prank, perm, tiletab, ntct);
  moe_fc1<<<8 * 20 * 6, 256, 0, stream>>>(xbf, W1cat, perm, wpair, bias1, tiletab, ntct, Hbuf);
  moe_fc2<<<8 * 20 * 8, 256, 0, stream>>>(Hbuf, W2cat, perm, wpair, b2, bs2, tiletab, ntct,
                                          (float*)d_out);
}

// Round 5
// 273.412 us; speedup vs baseline: 1.2096x; 1.2096x over previous
//
#include <hip/hip_runtime.h>
#include <cstdint>

#define TTOK 16384
#define HD   1024
#define NE   8
#define NDE  128
#define NDS  512
#define NC1  1536   // concat fc1 rows: E*DE routed + DS shared
#define KC2  1536   // concat fc2 cols in W2cat
#define NPAIR 28
#define MAXT  160   // max M-tiles over pair segments (<=128+27, padded to 8*20)
#define PREPB 3080
#define GATEB 4096
#define NH    768   // grouped hidden: 128(e1)+128(e2)+512(shared)
#define CSTRIDE 32  // cnt counter stride in ints (128 B: one cache line per pair)

typedef float  f32x4  __attribute__((ext_vector_type(4)));
typedef __bf16 bf16x8 __attribute__((ext_vector_type(8)));

__device__ __forceinline__ unsigned short f2bf(float f) {
  unsigned int u = __float_as_uint(f);
  u += 0x7fffu + ((u >> 16) & 1u);   // RNE; inputs finite
  return (unsigned short)(u >> 16);
}

__device__ __forceinline__ void gl2lds16(const void* gp, void* lp) {
  void* g0 = const_cast<void*>(gp);
  __builtin_amdgcn_global_load_lds((__attribute__((address_space(1))) void*)g0,
                                   (__attribute__((address_space(3))) void*)lp,
                                   16, 0, 0);
}

// ---------------- K1: fused weight prep + gate (pair id, rank, weights, x->bf16) ----------------
__global__ __launch_bounds__(256) void prep_gate(
    const float* __restrict__ x, const float* __restrict__ Wg,
    const float* __restrict__ W1, const float* __restrict__ Ws1,
    const float* __restrict__ W2, const float* __restrict__ Ws2,
    const float* __restrict__ b1, const float* __restrict__ bs1,
    unsigned short* __restrict__ W1cat, unsigned short* __restrict__ W2cat,
    float* __restrict__ bias1, unsigned short* __restrict__ xbf,
    float2* __restrict__ wpair, int* __restrict__ prank, int* __restrict__ cnt) {
  if (blockIdx.x < PREPB) {
    const int total = NC1 * HD + HD * KC2 + NC1;
    for (int idx = blockIdx.x * 256 + threadIdx.x; idx < total; idx += PREPB * 256) {
      if (idx < NC1 * HD) {
        int r = idx >> 10, k = idx & 1023;
        float v = (r < 1024) ? W1[idx] : Ws1[(size_t)(r - 1024) * HD + k];
        W1cat[idx] = f2bf(v);
      } else if (idx < NC1 * HD + HD * KC2) {
        int i2 = idx - NC1 * HD;
        int h = i2 / KC2;
        int j = i2 - h * KC2;
        float v = (j < 1024) ? W2[(size_t)((j >> 7) * HD + h) * NDE + (j & 127)]
                             : Ws2[(size_t)h * NDS + (j - 1024)];
        W2cat[i2] = f2bf(v);
      } else {
        int r = idx - (NC1 * HD + HD * KC2);
        bias1[r] = (r < 1024) ? b1[r] : bs1[r - 1024];
      }
    }
    return;
  }
  // ---- gate ----
  const int lane = threadIdx.x & 63;
  const int wv   = threadIdx.x >> 6;
  const int t    = (blockIdx.x - PREPB) * 4 + wv;

  const float* xr = x + (size_t)t * HD + lane * 16;
  float4 x0 = ((const float4*)xr)[0];
  float4 x1 = ((const float4*)xr)[1];
  float4 x2 = ((const float4*)xr)[2];
  float4 x3 = ((const float4*)xr)[3];

  unsigned short* xo = xbf + (size_t)t * HD + lane * 16;
  union { unsigned short us[8]; uint4 v; } pk;
  pk.us[0] = f2bf(x0.x); pk.us[1] = f2bf(x0.y); pk.us[2] = f2bf(x0.z); pk.us[3] = f2bf(x0.w);
  pk.us[4] = f2bf(x1.x); pk.us[5] = f2bf(x1.y); pk.us[6] = f2bf(x1.z); pk.us[7] = f2bf(x1.w);
  ((uint4*)xo)[0] = pk.v;
  pk.us[0] = f2bf(x2.x); pk.us[1] = f2bf(x2.y); pk.us[2] = f2bf(x2.z); pk.us[3] = f2bf(x2.w);
  pk.us[4] = f2bf(x3.x); pk.us[5] = f2bf(x3.y); pk.us[6] = f2bf(x3.z); pk.us[7] = f2bf(x3.w);
  ((uint4*)xo)[1] = pk.v;

  float lg[8];
#pragma unroll
  for (int e = 0; e < 8; ++e) {
    const float4* wr = (const float4*)(Wg + (size_t)e * HD + lane * 16);
    float4 a = wr[0], b = wr[1], c = wr[2], d = wr[3];
    lg[e] = a.x * x0.x + a.y * x0.y + a.z * x0.z + a.w * x0.w +
            b.x * x1.x + b.y * x1.y + b.z * x1.z + b.w * x1.w +
            c.x * x2.x + c.y * x2.y + c.z * x2.z + c.w * x2.w +
            d.x * x3.x + d.y * x3.y + d.z * x3.z + d.w * x3.w;
  }
#pragma unroll
  for (int off = 32; off > 0; off >>= 1) {
#pragma unroll
    for (int e = 0; e < 8; ++e) lg[e] += __shfl_xor(lg[e], off, 64);
  }

  if (lane == 0) {
    int i1 = 0; float m1 = lg[0];
#pragma unroll
    for (int e = 1; e < 8; ++e) { if (lg[e] > m1) { m1 = lg[e]; i1 = e; } }
    int i2 = -1; float m2 = -3.4e38f;
#pragma unroll
    for (int e = 0; e < 8; ++e) { if (e != i1 && lg[e] > m2) { m2 = lg[e]; i2 = e; } }
    float Z = 0.f;
#pragma unroll
    for (int e = 0; e < 8; ++e) Z += expf(lg[e] - m1);
    float s1 = 1.f / Z;
    float s2 = expf(m2 - m1) / Z;
    float dn = s1 + s2 + 1e-20f;
    float w1 = s1 / dn, w2 = s2 / dn;
    int ef, es; float wf, wsx;
    if (i1 < i2) { ef = i1; es = i2; wf = w1; wsx = w2; }
    else         { ef = i2; es = i1; wf = w2; wsx = w1; }
    int p = ef * 7 - (ef * (ef - 1)) / 2 + (es - ef - 1);   // C(8,2) index, ef<es
    int rank = atomicAdd(&cnt[p * CSTRIDE], 1);             // one cache line per pair
    wpair[t] = make_float2(wf, wsx);
    prank[t] = (p << 16) | rank;
  }
}

// ---------------- K2: scan counts, build perm + tile table ----------------
__global__ __launch_bounds__(256) void route_scan(const int* __restrict__ cnt,
                                                  const int* __restrict__ prank,
                                                  int* __restrict__ perm,
                                                  int4* __restrict__ tiletab,
                                                  int* __restrict__ ntct) {
  const int p = blockIdx.x;
  int c[NPAIR];
#pragma unroll
  for (int q = 0; q < NPAIR; ++q) c[q] = cnt[q * CSTRIDE];
  int estart = 0, tstart = 0;
  for (int q = 0; q < p; ++q) { estart += c[q]; tstart += (c[q] + 127) >> 7; }
  const int nt = (c[p] + 127) >> 7;
  if (p == NPAIR - 1 && threadIdx.x == 0) ntct[0] = tstart + nt;
  for (int k = threadIdx.x; k < nt; k += 256) {
    int4 e;
    e.x = p;
    e.y = estart + (k << 7);
    e.z = min(128, c[p] - (k << 7));
    e.w = (tstart + k) << 7;
    tiletab[tstart + k] = e;
  }
  for (int t = threadIdx.x; t < TTOK; t += 256) {
    int v = prank[t];
    if ((v >> 16) == p) perm[estart + (v & 0xffff)] = t;
  }
}

// ---------------- G1: grouped fc1: gather x rows, [128x768] per pair-tile ----------------
__global__ __launch_bounds__(256) void moe_fc1(const unsigned short* __restrict__ xbf,
                                               const unsigned short* __restrict__ W1cat,
                                               const int* __restrict__ perm,
                                               const float2* __restrict__ wpair,
                                               const float* __restrict__ bias1,
                                               const int4* __restrict__ tiletab,
                                               const int* __restrict__ ntct,
                                               unsigned short* __restrict__ Hbuf) {
  const int L   = blockIdx.x;
  const int xcd = L & 7;
  const int s   = L >> 3;
  const int mg  = s / 6;
  const int nn  = s - mg * 6;
  const int mt  = xcd + (mg << 3);
  if (mt >= ntct[0]) return;
  const int4 tt = tiletab[mt];
  const int eoff = tt.y, valid = tt.z, hbase = tt.w;
  int ef = 0, rem = tt.x;
  while (rem >= 7 - ef) { rem -= 7 - ef; ef++; }
  const int es = ef + 1 + rem;
  const int brow = (nn == 0) ? ef * 128 : (nn == 1) ? es * 128 : 1024 + ((nn - 2) << 7);

  __shared__ __align__(16) unsigned short As[128 * 64];
  __shared__ __align__(16) unsigned short Bs[128 * 64];

  const int tid  = threadIdx.x;
  const int lane = tid & 63;
  const int wv   = tid >> 6;
  const int wm   = wv >> 1;
  const int wn   = wv & 1;
  const int r16  = lane & 15;
  const int quad = lane >> 4;

  const unsigned short* gA[4];
  const unsigned short* gB[4];
  unsigned short* lA[4];
  unsigned short* lB[4];
#pragma unroll
  for (int i = 0; i < 4; ++i) {
    int idx = i * 256 + tid;
    int row = idx >> 3;
    int cc  = idx & 7;
    int kc  = cc ^ (row & 7);
    int tok = perm[eoff + min(row, valid - 1)];
    gA[i] = xbf + (size_t)tok * HD + kc * 8;
    gB[i] = W1cat + (size_t)(brow + row) * HD + kc * 8;
    lA[i] = As + idx * 8;
    lB[i] = Bs + idx * 8;
  }

  int aoff[4], boff[4];
#pragma unroll
  for (int i = 0; i < 4; ++i) {
    int ra = wm * 64 + i * 16 + r16;
    aoff[i] = ra * 64 + ((quad ^ (ra & 7)) << 3);
    int rb = wn * 64 + i * 16 + r16;
    boff[i] = rb * 64 + ((quad ^ (rb & 7)) << 3);
  }

  f32x4 acc[4][4];
#pragma unroll
  for (int i = 0; i < 4; ++i)
#pragma unroll
    for (int j = 0; j < 4; ++j) acc[i][j] = (f32x4){0.f, 0.f, 0.f, 0.f};

  for (int kt = 0; kt < 16; ++kt) {
    const int ko = kt << 6;
#pragma unroll
    for (int i = 0; i < 4; ++i) gl2lds16(gA[i] + ko, lA[i]);
#pragma unroll
    for (int i = 0; i < 4; ++i) gl2lds16(gB[i] + ko, lB[i]);
    __syncthreads();
#pragma unroll
    for (int g = 0; g < 2; ++g) {
      const int gx = g << 5;
      bf16x8 av[4], bv[4];
#pragma unroll
      for (int i = 0; i < 4; ++i) av[i] = *(const bf16x8*)(As + (aoff[i] ^ gx));
#pragma unroll
      for (int j = 0; j < 4; ++j) bv[j] = *(const bf16x8*)(Bs + (boff[j] ^ gx));
#pragma unroll
      for (int i = 0; i < 4; ++i)
#pragma unroll
        for (int j = 0; j < 4; ++j)
          acc[i][j] = __builtin_amdgcn_mfma_f32_16x16x32_bf16(av[i], bv[j], acc[i][j], 0, 0, 0);
    }
    __syncthreads();
  }

  // epilogue: relu(acc+b)*scale, scale = w1/w2/1 by nn
  float* wl = (float*)As;
  if (tid < 128) {
    int tok = perm[eoff + min(tid, valid - 1)];
    float sc = 1.0f;
    if (nn == 0) sc = wpair[tok].x;
    else if (nn == 1) sc = wpair[tok].y;
    wl[tid] = sc;
  }
  __syncthreads();
#pragma unroll
  for (int j = 0; j < 4; ++j) {
    const int cin = wn * 64 + j * 16 + r16;
    const float bz = bias1[brow + cin];
#pragma unroll
    for (int i = 0; i < 4; ++i) {
#pragma unroll
      for (int r = 0; r < 4; ++r) {
        const int lrow = wm * 64 + i * 16 + quad * 4 + r;
        float v = fmaxf(acc[i][j][r] + bz, 0.f) * wl[lrow];
        Hbuf[(size_t)(hbase + lrow) * NH + nn * 128 + cin] = f2bf(v);
      }
    }
  }
}

// ---------------- G2: grouped fc2: [128 tokens] x [128 h-cols], K=768, scatter out ----------------
__global__ __launch_bounds__(256) void moe_fc2(const unsigned short* __restrict__ Hbuf,
                                               const unsigned short* __restrict__ W2cat,
                                               const int* __restrict__ perm,
                                               const float2* __restrict__ wpair,
                                               const float* __restrict__ b2,
                                               const float* __restrict__ bs2,
                                               const int4* __restrict__ tiletab,
                                               const int* __restrict__ ntct,
                                               float* __restrict__ out) {
  const int L   = blockIdx.x;
  const int xcd = L & 7;
  const int s   = L >> 3;
  const int mg  = s >> 3;
  const int nn  = s & 7;
  const int mt  = xcd + (mg << 3);
  if (mt >= ntct[0]) return;
  const int4 tt = tiletab[mt];
  const int eoff = tt.y, valid = tt.z, hbase = tt.w;
  int ef = 0, rem = tt.x;
  while (rem >= 7 - ef) { rem -= 7 - ef; ef++; }
  const int es = ef + 1 + rem;
  const int tileN = nn << 7;

  __shared__ __align__(16) unsigned short As[128 * 64];
  __shared__ __align__(16) unsigned short Bs[128 * 64];

  const int tid  = threadIdx.x;
  const int lane = tid & 63;
  const int wv   = tid >> 6;
  const int wm   = wv >> 1;
  const int wn   = wv & 1;
  const int r16  = lane & 15;
  const int quad = lane >> 4;

  const unsigned short* gA[4];
  const unsigned short* gB[4];
  unsigned short* lA[4];
  unsigned short* lB[4];
#pragma unroll
  for (int i = 0; i < 4; ++i) {
    int idx = i * 256 + tid;
    int row = idx >> 3;
    int cc  = idx & 7;
    int kc  = cc ^ (row & 7);
    gA[i] = Hbuf + (size_t)(hbase + row) * NH + kc * 8;
    gB[i] = W2cat + (size_t)(tileN + row) * KC2 + kc * 8;
    lA[i] = As + idx * 8;
    lB[i] = Bs + idx * 8;
  }

  int aoff[4], boff[4];
#pragma unroll
  for (int i = 0; i < 4; ++i) {
    int ra = wm * 64 + i * 16 + r16;
    aoff[i] = ra * 64 + ((quad ^ (ra & 7)) << 3);
    int rb = wn * 64 + i * 16 + r16;
    boff[i] = rb * 64 + ((quad ^ (rb & 7)) << 3);
  }

  f32x4 acc[4][4];
#pragma unroll
  for (int i = 0; i < 4; ++i)
#pragma unroll
    for (int j = 0; j < 4; ++j) acc[i][j] = (f32x4){0.f, 0.f, 0.f, 0.f};

  for (int kt = 0; kt < 12; ++kt) {
    const int koA = kt << 6;
    const int koB = (kt < 2) ? ef * 128 + (kt << 6)
                 : (kt < 4) ? es * 128 + ((kt - 2) << 6)
                            : 1024 + ((kt - 4) << 6);
#pragma unroll
    for (int i = 0; i < 4; ++i) gl2lds16(gA[i] + koA, lA[i]);
#pragma unroll
    for (int i = 0; i < 4; ++i) gl2lds16(gB[i] + koB, lB[i]);
    __syncthreads();
#pragma unroll
    for (int g = 0; g < 2; ++g) {
      const int gx = g << 5;
      bf16x8 av[4], bv[4];
#pragma unroll
      for (int i = 0; i < 4; ++i) av[i] = *(const bf16x8*)(As + (aoff[i] ^ gx));
#pragma unroll
      for (int j = 0; j < 4; ++j) bv[j] = *(const bf16x8*)(Bs + (boff[j] ^ gx));
#pragma unroll
      for (int i = 0; i < 4; ++i)
#pragma unroll
        for (int j = 0; j < 4; ++j)
          acc[i][j] = __builtin_amdgcn_mfma_f32_16x16x32_bf16(av[i], bv[j], acc[i][j], 0, 0, 0);
    }
    __syncthreads();
  }

  // epilogue: + bs2 + w1*b2[e1] + w2*b2[e2], scatter to out[token]
  float2* wl2 = (float2*)As;
  int* tokl   = (int*)Bs;
  if (tid < 128) {
    int tokc = perm[eoff + min(tid, valid - 1)];
    tokl[tid] = (tid < valid) ? tokc : -1;
    wl2[tid] = wpair[tokc];
  }
  __syncthreads();
  float bsc[4], b2a[4], b2b[4];
#pragma unroll
  for (int j = 0; j < 4; ++j) {
    const int col = tileN + wn * 64 + j * 16 + r16;
    bsc[j] = bs2[col];
    b2a[j] = b2[(size_t)ef * HD + col];
    b2b[j] = b2[(size_t)es * HD + col];
  }
#pragma unroll
  for (int i = 0; i < 4; ++i) {
#pragma unroll
    for (int r = 0; r < 4; ++r) {
      const int lrow = wm * 64 + i * 16 + quad * 4 + r;
      const int tok = tokl[lrow];
      if (tok < 0) continue;
      const float2 w = wl2[lrow];
#pragma unroll
      for (int j = 0; j < 4; ++j) {
        const int col = tileN + wn * 64 + j * 16 + r16;
        out[(size_t)tok * HD + col] = acc[i][j][r] + bsc[j] + w.x * b2a[j] + w.y * b2b[j];
      }
    }
  }
}

extern "C" void kernel_launch(void* const* d_in, const int* in_sizes, int n_in,
                              void* d_out, int out_size, void* d_ws, size_t ws_size,
                              hipStream_t stream) {
  const float* x   = (const float*)d_in[0];
  const float* Wg  = (const float*)d_in[1];
  const float* W1  = (const float*)d_in[2];
  const float* b1  = (const float*)d_in[3];
  const float* W2  = (const float*)d_in[4];
  const float* b2  = (const float*)d_in[5];
  const float* Ws1 = (const float*)d_in[6];
  const float* bs1 = (const float*)d_in[7];
  const float* Ws2 = (const float*)d_in[8];
  const float* bs2 = (const float*)d_in[9];

  char* ws = (char*)d_ws;
  size_t off = 0;
  unsigned short* xbf   = (unsigned short*)(ws + off); off += (size_t)TTOK * HD * 2;       // 32 MiB
  unsigned short* Hbuf  = (unsigned short*)(ws + off); off += (size_t)MAXT * 128 * NH * 2; // 30 MiB
  unsigned short* W1cat = (unsigned short*)(ws + off); off += (size_t)NC1 * HD * 2;
  unsigned short* W2cat = (unsigned short*)(ws + off); off += (size_t)HD * KC2 * 2;
  float* bias1          = (float*)(ws + off);          off += (size_t)NC1 * 4;
  float2* wpair         = (float2*)(ws + off);         off += (size_t)TTOK * 8;
  int* prank            = (int*)(ws + off);            off += (size_t)TTOK * 4;
  int* perm             = (int*)(ws + off);            off += (size_t)TTOK * 4;
  int4* tiletab         = (int4*)(ws + off);           off += (size_t)MAXT * 16;
  int* cnt              = (int*)(ws + off);            off += (size_t)NPAIR * CSTRIDE * 4;
  int* ntct             = (int*)(ws + off);            off += 16;

  hipMemsetAsync(cnt, 0, NPAIR * CSTRIDE * 4, stream);
  prep_gate<<<PREPB + GATEB, 256, 0, stream>>>(x, Wg, W1, Ws1, W2, Ws2, b1, bs1,
                                               W1cat, W2cat, bias1, xbf, wpair, prank, cnt);
  route_scan<<<NPAIR, 256, 0, stream>>>(cnt, prank, perm, tiletab, ntct);
  moe_fc1<<<8 * 20 * 6, 256, 0, stream>>>(xbf, W1cat, perm, wpair, bias1, tiletab, ntct, Hbuf);
  moe_fc2<<<8 * 20 * 8, 256, 0, stream>>>(Hbuf, W2cat, perm, wpair, b2, bs2, tiletab, ntct,
                                          (float*)d_out);
}

// Round 6
// 270.171 us; speedup vs baseline: 1.2241x; 1.0120x over previous
//
#include <hip/hip_runtime.h>
#include <cstdint>

#define TTOK 16384
#define HD   1024
#define NE   8
#define NDE  128
#define NDS  512
#define NC1  1536   // concat fc1 rows: E*DE routed + DS shared
#define KC2  1536   // concat fc2 cols in W2cat
#define NPAIR 28
#define MAXT  160   // max M-tiles over pair segments (<=128+27, padded to 8*20)
#define PREPB 3080
#define GATEB 4096
#define NH    768   // grouped hidden: 128(e1)+128(e2)+512(shared)

typedef float  f32x4  __attribute__((ext_vector_type(4)));
typedef __bf16 bf16x8 __attribute__((ext_vector_type(8)));

__device__ __forceinline__ unsigned short f2bf(float f) {
  unsigned int u = __float_as_uint(f);
  u += 0x7fffu + ((u >> 16) & 1u);   // RNE; inputs finite
  return (unsigned short)(u >> 16);
}

__device__ __forceinline__ void gl2lds16(const void* gp, void* lp) {
  void* g0 = const_cast<void*>(gp);
  __builtin_amdgcn_global_load_lds((__attribute__((address_space(1))) void*)g0,
                                   (__attribute__((address_space(3))) void*)lp,
                                   16, 0, 0);
}

// ---------------- K1: fused weight prep + gate (pair id, weights, x->bf16) ----------------
// No atomics: rank assignment is deferred to route_scan (order within a pair is
// semantically irrelevant -- perm only needs to be a bijection).
__global__ __launch_bounds__(256) void prep_gate(
    const float* __restrict__ x, const float* __restrict__ Wg,
    const float* __restrict__ W1, const float* __restrict__ Ws1,
    const float* __restrict__ W2, const float* __restrict__ Ws2,
    const float* __restrict__ b1, const float* __restrict__ bs1,
    unsigned short* __restrict__ W1cat, unsigned short* __restrict__ W2cat,
    float* __restrict__ bias1, unsigned short* __restrict__ xbf,
    float2* __restrict__ wpair, int* __restrict__ pid) {
  if (blockIdx.x < PREPB) {
    const int total = NC1 * HD + HD * KC2 + NC1;
    for (int idx = blockIdx.x * 256 + threadIdx.x; idx < total; idx += PREPB * 256) {
      if (idx < NC1 * HD) {
        int r = idx >> 10, k = idx & 1023;
        float v = (r < 1024) ? W1[idx] : Ws1[(size_t)(r - 1024) * HD + k];
        W1cat[idx] = f2bf(v);
      } else if (idx < NC1 * HD + HD * KC2) {
        int i2 = idx - NC1 * HD;
        int h = i2 / KC2;
        int j = i2 - h * KC2;
        float v = (j < 1024) ? W2[(size_t)((j >> 7) * HD + h) * NDE + (j & 127)]
                             : Ws2[(size_t)h * NDS + (j - 1024)];
        W2cat[i2] = f2bf(v);
      } else {
        int r = idx - (NC1 * HD + HD * KC2);
        bias1[r] = (r < 1024) ? b1[r] : bs1[r - 1024];
      }
    }
    return;
  }
  // ---- gate ----
  const int lane = threadIdx.x & 63;
  const int wv   = threadIdx.x >> 6;
  const int t    = (blockIdx.x - PREPB) * 4 + wv;

  const float* xr = x + (size_t)t * HD + lane * 16;
  float4 x0 = ((const float4*)xr)[0];
  float4 x1 = ((const float4*)xr)[1];
  float4 x2 = ((const float4*)xr)[2];
  float4 x3 = ((const float4*)xr)[3];

  unsigned short* xo = xbf + (size_t)t * HD + lane * 16;
  union { unsigned short us[8]; uint4 v; } pk;
  pk.us[0] = f2bf(x0.x); pk.us[1] = f2bf(x0.y); pk.us[2] = f2bf(x0.z); pk.us[3] = f2bf(x0.w);
  pk.us[4] = f2bf(x1.x); pk.us[5] = f2bf(x1.y); pk.us[6] = f2bf(x1.z); pk.us[7] = f2bf(x1.w);
  ((uint4*)xo)[0] = pk.v;
  pk.us[0] = f2bf(x2.x); pk.us[1] = f2bf(x2.y); pk.us[2] = f2bf(x2.z); pk.us[3] = f2bf(x2.w);
  pk.us[4] = f2bf(x3.x); pk.us[5] = f2bf(x3.y); pk.us[6] = f2bf(x3.z); pk.us[7] = f2bf(x3.w);
  ((uint4*)xo)[1] = pk.v;

  float lg[8];
#pragma unroll
  for (int e = 0; e < 8; ++e) {
    const float4* wr = (const float4*)(Wg + (size_t)e * HD + lane * 16);
    float4 a = wr[0], b = wr[1], c = wr[2], d = wr[3];
    lg[e] = a.x * x0.x + a.y * x0.y + a.z * x0.z + a.w * x0.w +
            b.x * x1.x + b.y * x1.y + b.z * x1.z + b.w * x1.w +
            c.x * x2.x + c.y * x2.y + c.z * x2.z + c.w * x2.w +
            d.x * x3.x + d.y * x3.y + d.z * x3.z + d.w * x3.w;
  }
#pragma unroll
  for (int off = 32; off > 0; off >>= 1) {
#pragma unroll
    for (int e = 0; e < 8; ++e) lg[e] += __shfl_xor(lg[e], off, 64);
  }

  if (lane == 0) {
    int i1 = 0; float m1 = lg[0];
#pragma unroll
    for (int e = 1; e < 8; ++e) { if (lg[e] > m1) { m1 = lg[e]; i1 = e; } }
    int i2 = -1; float m2 = -3.4e38f;
#pragma unroll
    for (int e = 0; e < 8; ++e) { if (e != i1 && lg[e] > m2) { m2 = lg[e]; i2 = e; } }
    float Z = 0.f;
#pragma unroll
    for (int e = 0; e < 8; ++e) Z += expf(lg[e] - m1);
    float s1 = 1.f / Z;
    float s2 = expf(m2 - m1) / Z;
    float dn = s1 + s2 + 1e-20f;
    float w1 = s1 / dn, w2 = s2 / dn;
    int ef, es; float wf, wsx;
    if (i1 < i2) { ef = i1; es = i2; wf = w1; wsx = w2; }
    else         { ef = i2; es = i1; wf = w2; wsx = w1; }
    int p = ef * 7 - (ef * (ef - 1)) / 2 + (es - ef - 1);   // C(8,2) index, ef<es
    wpair[t] = make_float2(wf, wsx);
    pid[t] = p;
  }
}

// ---------------- K2: atomic-free routing: histogram + prefix + rank assignment ----------------
// One block per pair. Strips are interleaved (token t ≡ tid mod 256) for coalescing.
__global__ __launch_bounds__(256) void route_scan(const int* __restrict__ pid,
                                                  int* __restrict__ perm,
                                                  int4* __restrict__ tiletab,
                                                  int* __restrict__ ntct) {
  __shared__ int hist[256 * 29];
  __shared__ int totals[NPAIR];
  __shared__ int spre[256];
  const int p   = blockIdx.x;
  const int tid = threadIdx.x;
#pragma unroll
  for (int q = 0; q < 29; ++q) hist[tid * 29 + q] = 0;
  __syncthreads();
  for (int k = 0; k < 64; ++k) {
    int q = pid[tid + (k << 8)];
    hist[tid * 29 + q]++;
  }
  __syncthreads();
  if (tid < NPAIR) {
    int s = 0;
    for (int i = 0; i < 256; ++i) s += hist[i * 29 + tid];
    totals[tid] = s;
  }
  __syncthreads();
  const int mycnt = hist[tid * 29 + p];
  spre[tid] = mycnt;
  __syncthreads();
  for (int d = 1; d < 256; d <<= 1) {       // inclusive Hillis-Steele scan
    int add = (tid >= d) ? spre[tid - d] : 0;
    __syncthreads();
    spre[tid] += add;
    __syncthreads();
  }
  int estart = 0, tstart = 0;
  for (int q = 0; q < p; ++q) { estart += totals[q]; tstart += (totals[q] + 127) >> 7; }
  const int cp = totals[p];
  const int nt = (cp + 127) >> 7;
  if (p == NPAIR - 1 && tid == 0) ntct[0] = tstart + nt;
  for (int k = tid; k < nt; k += 256) {
    int4 e;
    e.x = p;
    e.y = estart + (k << 7);
    e.z = min(128, cp - (k << 7));
    e.w = (tstart + k) << 7;
    tiletab[tstart + k] = e;
  }
  int wr = estart + spre[tid] - mycnt;
  for (int k = 0; k < 64; ++k) {
    int t = tid + (k << 8);
    if (pid[t] == p) perm[wr++] = t;
  }
}

// ---------------- G1: grouped fc1: gather x rows, [128x768] per pair-tile ----------------
__global__ __launch_bounds__(256) void moe_fc1(const unsigned short* __restrict__ xbf,
                                               const unsigned short* __restrict__ W1cat,
                                               const int* __restrict__ perm,
                                               const float2* __restrict__ wpair,
                                               const float* __restrict__ bias1,
                                               const int4* __restrict__ tiletab,
                                               const int* __restrict__ ntct,
                                               unsigned short* __restrict__ Hbuf) {
  const int L   = blockIdx.x;
  const int xcd = L & 7;
  const int s   = L >> 3;
  const int mg  = s / 6;
  const int nn  = s - mg * 6;
  const int mt  = xcd + (mg << 3);
  if (mt >= ntct[0]) return;
  const int4 tt = tiletab[mt];
  const int eoff = tt.y, valid = tt.z, hbase = tt.w;
  int ef = 0, rem = tt.x;
  while (rem >= 7 - ef) { rem -= 7 - ef; ef++; }
  const int es = ef + 1 + rem;
  const int brow = (nn == 0) ? ef * 128 : (nn == 1) ? es * 128 : 1024 + ((nn - 2) << 7);

  __shared__ __align__(16) unsigned short As[128 * 64];
  __shared__ __align__(16) unsigned short Bs[128 * 64];

  const int tid  = threadIdx.x;
  const int lane = tid & 63;
  const int wv   = tid >> 6;
  const int wm   = wv >> 1;
  const int wn   = wv & 1;
  const int r16  = lane & 15;
  const int quad = lane >> 4;

  const unsigned short* gA[4];
  const unsigned short* gB[4];
  unsigned short* lA[4];
  unsigned short* lB[4];
#pragma unroll
  for (int i = 0; i < 4; ++i) {
    int idx = i * 256 + tid;
    int row = idx >> 3;
    int cc  = idx & 7;
    int kc  = cc ^ (row & 7);
    int tok = perm[eoff + min(row, valid - 1)];
    gA[i] = xbf + (size_t)tok * HD + kc * 8;
    gB[i] = W1cat + (size_t)(brow + row) * HD + kc * 8;
    lA[i] = As + idx * 8;
    lB[i] = Bs + idx * 8;
  }

  int aoff[4], boff[4];
#pragma unroll
  for (int i = 0; i < 4; ++i) {
    int ra = wm * 64 + i * 16 + r16;
    aoff[i] = ra * 64 + ((quad ^ (ra & 7)) << 3);
    int rb = wn * 64 + i * 16 + r16;
    boff[i] = rb * 64 + ((quad ^ (rb & 7)) << 3);
  }

  f32x4 acc[4][4];
#pragma unroll
  for (int i = 0; i < 4; ++i)
#pragma unroll
    for (int j = 0; j < 4; ++j) acc[i][j] = (f32x4){0.f, 0.f, 0.f, 0.f};

  for (int kt = 0; kt < 16; ++kt) {
    const int ko = kt << 6;
#pragma unroll
    for (int i = 0; i < 4; ++i) gl2lds16(gA[i] + ko, lA[i]);
#pragma unroll
    for (int i = 0; i < 4; ++i) gl2lds16(gB[i] + ko, lB[i]);
    __syncthreads();
#pragma unroll
    for (int g = 0; g < 2; ++g) {
      const int gx = g << 5;
      bf16x8 av[4], bv[4];
#pragma unroll
      for (int i = 0; i < 4; ++i) av[i] = *(const bf16x8*)(As + (aoff[i] ^ gx));
#pragma unroll
      for (int j = 0; j < 4; ++j) bv[j] = *(const bf16x8*)(Bs + (boff[j] ^ gx));
#pragma unroll
      for (int i = 0; i < 4; ++i)
#pragma unroll
        for (int j = 0; j < 4; ++j)
          acc[i][j] = __builtin_amdgcn_mfma_f32_16x16x32_bf16(av[i], bv[j], acc[i][j], 0, 0, 0);
    }
    __syncthreads();
  }

  // epilogue: relu(acc+b)*scale, scale = w1/w2/1 by nn
  float* wl = (float*)As;
  if (tid < 128) {
    int tok = perm[eoff + min(tid, valid - 1)];
    float sc = 1.0f;
    if (nn == 0) sc = wpair[tok].x;
    else if (nn == 1) sc = wpair[tok].y;
    wl[tid] = sc;
  }
  __syncthreads();
#pragma unroll
  for (int j = 0; j < 4; ++j) {
    const int cin = wn * 64 + j * 16 + r16;
    const float bz = bias1[brow + cin];
#pragma unroll
    for (int i = 0; i < 4; ++i) {
#pragma unroll
      for (int r = 0; r < 4; ++r) {
        const int lrow = wm * 64 + i * 16 + quad * 4 + r;
        float v = fmaxf(acc[i][j][r] + bz, 0.f) * wl[lrow];
        Hbuf[(size_t)(hbase + lrow) * NH + nn * 128 + cin] = f2bf(v);
      }
    }
  }
}

// ---------------- G2: grouped fc2: [128 tokens] x [128 h-cols], K=768, scatter out ----------------
__global__ __launch_bounds__(256) void moe_fc2(const unsigned short* __restrict__ Hbuf,
                                               const unsigned short* __restrict__ W2cat,
                                               const int* __restrict__ perm,
                                               const float2* __restrict__ wpair,
                                               const float* __restrict__ b2,
                                               const float* __restrict__ bs2,
                                               const int4* __restrict__ tiletab,
                                               const int* __restrict__ ntct,
                                               float* __restrict__ out) {
  const int L   = blockIdx.x;
  const int xcd = L & 7;
  const int s   = L >> 3;
  const int mg  = s >> 3;
  const int nn  = s & 7;
  const int mt  = xcd + (mg << 3);
  if (mt >= ntct[0]) return;
  const int4 tt = tiletab[mt];
  const int eoff = tt.y, valid = tt.z, hbase = tt.w;
  int ef = 0, rem = tt.x;
  while (rem >= 7 - ef) { rem -= 7 - ef; ef++; }
  const int es = ef + 1 + rem;
  const int tileN = nn << 7;

  __shared__ __align__(16) unsigned short As[128 * 64];
  __shared__ __align__(16) unsigned short Bs[128 * 64];

  const int tid  = threadIdx.x;
  const int lane = tid & 63;
  const int wv   = tid >> 6;
  const int wm   = wv >> 1;
  const int wn   = wv & 1;
  const int r16  = lane & 15;
  const int quad = lane >> 4;

  const unsigned short* gA[4];
  const unsigned short* gB[4];
  unsigned short* lA[4];
  unsigned short* lB[4];
#pragma unroll
  for (int i = 0; i < 4; ++i) {
    int idx = i * 256 + tid;
    int row = idx >> 3;
    int cc  = idx & 7;
    int kc  = cc ^ (row & 7);
    gA[i] = Hbuf + (size_t)(hbase + row) * NH + kc * 8;
    gB[i] = W2cat + (size_t)(tileN + row) * KC2 + kc * 8;
    lA[i] = As + idx * 8;
    lB[i] = Bs + idx * 8;
  }

  int aoff[4], boff[4];
#pragma unroll
  for (int i = 0; i < 4; ++i) {
    int ra = wm * 64 + i * 16 + r16;
    aoff[i] = ra * 64 + ((quad ^ (ra & 7)) << 3);
    int rb = wn * 64 + i * 16 + r16;
    boff[i] = rb * 64 + ((quad ^ (rb & 7)) << 3);
  }

  f32x4 acc[4][4];
#pragma unroll
  for (int i = 0; i < 4; ++i)
#pragma unroll
    for (int j = 0; j < 4; ++j) acc[i][j] = (f32x4){0.f, 0.f, 0.f, 0.f};

  for (int kt = 0; kt < 12; ++kt) {
    const int koA = kt << 6;
    const int koB = (kt < 2) ? ef * 128 + (kt << 6)
                 : (kt < 4) ? es * 128 + ((kt - 2) << 6)
                            : 1024 + ((kt - 4) << 6);
#pragma unroll
    for (int i = 0; i < 4; ++i) gl2lds16(gA[i] + koA, lA[i]);
#pragma unroll
    for (int i = 0; i < 4; ++i) gl2lds16(gB[i] + koB, lB[i]);
    __syncthreads();
#pragma unroll
    for (int g = 0; g < 2; ++g) {
      const int gx = g << 5;
      bf16x8 av[4], bv[4];
#pragma unroll
      for (int i = 0; i < 4; ++i) av[i] = *(const bf16x8*)(As + (aoff[i] ^ gx));
#pragma unroll
      for (int j = 0; j < 4; ++j) bv[j] = *(const bf16x8*)(Bs + (boff[j] ^ gx));
#pragma unroll
      for (int i = 0; i < 4; ++i)
#pragma unroll
        for (int j = 0; j < 4; ++j)
          acc[i][j] = __builtin_amdgcn_mfma_f32_16x16x32_bf16(av[i], bv[j], acc[i][j], 0, 0, 0);
    }
    __syncthreads();
  }

  // epilogue: + bs2 + w1*b2[e1] + w2*b2[e2], scatter to out[token]
  float2* wl2 = (float2*)As;
  int* tokl   = (int*)Bs;
  if (tid < 128) {
    int tokc = perm[eoff + min(tid, valid - 1)];
    tokl[tid] = (tid < valid) ? tokc : -1;
    wl2[tid] = wpair[tokc];
  }
  __syncthreads();
  float bsc[4], b2a[4], b2b[4];
#pragma unroll
  for (int j = 0; j < 4; ++j) {
    const int col = tileN + wn * 64 + j * 16 + r16;
    bsc[j] = bs2[col];
    b2a[j] = b2[(size_t)ef * HD + col];
    b2b[j] = b2[(size_t)es * HD + col];
  }
#pragma unroll
  for (int i = 0; i < 4; ++i) {
#pragma unroll
    for (int r = 0; r < 4; ++r) {
      const int lrow = wm * 64 + i * 16 + quad * 4 + r;
      const int tok = tokl[lrow];
      if (tok < 0) continue;
      const float2 w = wl2[lrow];
#pragma unroll
      for (int j = 0; j < 4; ++j) {
        const int col = tileN + wn * 64 + j * 16 + r16;
        out[(size_t)tok * HD + col] = acc[i][j][r] + bsc[j] + w.x * b2a[j] + w.y * b2b[j];
      }
    }
  }
}

extern "C" void kernel_launch(void* const* d_in, const int* in_sizes, int n_in,
                              void* d_out, int out_size, void* d_ws, size_t ws_size,
                              hipStream_t stream) {
  const float* x   = (const float*)d_in[0];
  const float* Wg  = (const float*)d_in[1];
  const float* W1  = (const float*)d_in[2];
  const float* b1  = (const float*)d_in[3];
  const float* W2  = (const float*)d_in[4];
  const float* b2  = (const float*)d_in[5];
  const float* Ws1 = (const float*)d_in[6];
  const float* bs1 = (const float*)d_in[7];
  const float* Ws2 = (const float*)d_in[8];
  const float* bs2 = (const float*)d_in[9];

  char* ws = (char*)d_ws;
  size_t off = 0;
  unsigned short* xbf   = (unsigned short*)(ws + off); off += (size_t)TTOK * HD * 2;       // 32 MiB
  unsigned short* Hbuf  = (unsigned short*)(ws + off); off += (size_t)MAXT * 128 * NH * 2; // 30 MiB
  unsigned short* W1cat = (unsigned short*)(ws + off); off += (size_t)NC1 * HD * 2;
  unsigned short* W2cat = (unsigned short*)(ws + off); off += (size_t)HD * KC2 * 2;
  float* bias1          = (float*)(ws + off);          off += (size_t)NC1 * 4;
  float2* wpair         = (float2*)(ws + off);         off += (size_t)TTOK * 8;
  int* pid              = (int*)(ws + off);            off += (size_t)TTOK * 4;
  int* perm             = (int*)(ws + off);            off += (size_t)TTOK * 4;
  int4* tiletab         = (int4*)(ws + off);           off += (size_t)MAXT * 16;
  int* ntct             = (int*)(ws + off);            off += 16;

  prep_gate<<<PREPB + GATEB, 256, 0, stream>>>(x, Wg, W1, Ws1, W2, Ws2, b1, bs1,
                                               W1cat, W2cat, bias1, xbf, wpair, pid);
  route_scan<<<NPAIR, 256, 0, stream>>>(pid, perm, tiletab, ntct);
  moe_fc1<<<8 * 20 * 6, 256, 0, stream>>>(xbf, W1cat, perm, wpair, bias1, tiletab, ntct, Hbuf);
  moe_fc2<<<8 * 20 * 8, 256, 0, stream>>>(Hbuf, W2cat, perm, wpair, b2, bs2, tiletab, ntct,
                                          (float*)d_out);
}

// Round 7
// 252.732 us; speedup vs baseline: 1.3085x; 1.0690x over previous
//
#include <hip/hip_runtime.h>
#include <cstdint>

#define TTOK 16384
#define HD   1024
#define NE   8
#define NDE  128
#define NDS  512
#define NC1  1536   // concat fc1 rows: E*DE routed + DS shared
#define KC2  1536   // concat fc2 cols in W2cat
#define NPAIR 28
#define MAXT  160   // max M-tiles over pair segments (<=128+27, padded to 8*20)
#define PREPB 3080
#define GATEB 1024  // 16 tokens per block
#define NH    768   // grouped hidden: 128(e1)+128(e2)+512(shared)

typedef float  f32x4  __attribute__((ext_vector_type(4)));
typedef __bf16 bf16x8 __attribute__((ext_vector_type(8)));

__device__ __forceinline__ unsigned short f2bf(float f) {
  unsigned int u = __float_as_uint(f);
  u += 0x7fffu + ((u >> 16) & 1u);   // RNE; inputs finite
  return (unsigned short)(u >> 16);
}

__device__ __forceinline__ void gl2lds16(const void* gp, void* lp) {
  void* g0 = const_cast<void*>(gp);
  __builtin_amdgcn_global_load_lds((__attribute__((address_space(1))) void*)g0,
                                   (__attribute__((address_space(3))) void*)lp,
                                   16, 0, 0);
}

// ---------------- K1: fused weight prep + gate (pair id, weights, x->bf16) ----------------
// Gate v2: 16 tokens/block, 4 tokens/wave. Batched x loads (16 in flight/wave),
// Wg reuse across 4 tokens, LDS-transpose reduction (no shuffle chains).
__global__ __launch_bounds__(256) void prep_gate(
    const float* __restrict__ x, const float* __restrict__ Wg,
    const float* __restrict__ W1, const float* __restrict__ Ws1,
    const float* __restrict__ W2, const float* __restrict__ Ws2,
    const float* __restrict__ b1, const float* __restrict__ bs1,
    unsigned short* __restrict__ W1cat, unsigned short* __restrict__ W2cat,
    float* __restrict__ bias1, unsigned short* __restrict__ xbf,
    float2* __restrict__ wpair, int* __restrict__ pid) {
  if (blockIdx.x < PREPB) {
    const int total = NC1 * HD + HD * KC2 + NC1;
    for (int idx = blockIdx.x * 256 + threadIdx.x; idx < total; idx += PREPB * 256) {
      if (idx < NC1 * HD) {
        int r = idx >> 10, k = idx & 1023;
        float v = (r < 1024) ? W1[idx] : Ws1[(size_t)(r - 1024) * HD + k];
        W1cat[idx] = f2bf(v);
      } else if (idx < NC1 * HD + HD * KC2) {
        int i2 = idx - NC1 * HD;
        int h = i2 / KC2;
        int j = i2 - h * KC2;
        float v = (j < 1024) ? W2[(size_t)((j >> 7) * HD + h) * NDE + (j & 127)]
                             : Ws2[(size_t)h * NDS + (j - 1024)];
        W2cat[i2] = f2bf(v);
      } else {
        int r = idx - (NC1 * HD + HD * KC2);
        bias1[r] = (r < 1024) ? b1[r] : bs1[r - 1024];
      }
    }
    return;
  }
  // ---- gate: block handles 16 tokens ----
  __shared__ float part[16 * 8 * 64];   // 32 KB: [job=(tok*8+e)][lane] rotated
  __shared__ float lgs[128];

  const int tid  = threadIdx.x;
  const int lane = tid & 63;
  const int wv   = tid >> 6;
  const int g    = blockIdx.x - PREPB;
  const int tokb = g * 16 + wv * 4;

  // batched loads: 4 tokens x 4 float4 (16 outstanding)
  const float* xr = x + (size_t)tokb * HD + lane * 16;
  float4 xv[4][4];
#pragma unroll
  for (int t = 0; t < 4; ++t)
#pragma unroll
    for (int c = 0; c < 4; ++c)
      xv[t][c] = ((const float4*)(xr + (size_t)t * HD))[c];

  // xbf stores (2 uint4 per token per lane)
#pragma unroll
  for (int t = 0; t < 4; ++t) {
    unsigned short* xo = xbf + (size_t)(tokb + t) * HD + lane * 16;
    union { unsigned short us[8]; uint4 v; } pk;
    pk.us[0] = f2bf(xv[t][0].x); pk.us[1] = f2bf(xv[t][0].y);
    pk.us[2] = f2bf(xv[t][0].z); pk.us[3] = f2bf(xv[t][0].w);
    pk.us[4] = f2bf(xv[t][1].x); pk.us[5] = f2bf(xv[t][1].y);
    pk.us[6] = f2bf(xv[t][1].z); pk.us[7] = f2bf(xv[t][1].w);
    ((uint4*)xo)[0] = pk.v;
    pk.us[0] = f2bf(xv[t][2].x); pk.us[1] = f2bf(xv[t][2].y);
    pk.us[2] = f2bf(xv[t][2].z); pk.us[3] = f2bf(xv[t][2].w);
    pk.us[4] = f2bf(xv[t][3].x); pk.us[5] = f2bf(xv[t][3].y);
    pk.us[6] = f2bf(xv[t][3].z); pk.us[7] = f2bf(xv[t][3].w);
    ((uint4*)xo)[1] = pk.v;
  }

  // dots: e outer (Wg loaded once per e, reused for 4 tokens)
  float p[4][8];
#pragma unroll
  for (int t = 0; t < 4; ++t)
#pragma unroll
    for (int e = 0; e < 8; ++e) p[t][e] = 0.f;
#pragma unroll
  for (int e = 0; e < 8; ++e) {
    const float4* wr = (const float4*)(Wg + (size_t)e * HD + lane * 16);
    float4 w0 = wr[0], w1 = wr[1], w2 = wr[2], w3 = wr[3];
#pragma unroll
    for (int t = 0; t < 4; ++t) {
      p[t][e] = w0.x * xv[t][0].x + w0.y * xv[t][0].y + w0.z * xv[t][0].z + w0.w * xv[t][0].w +
                w1.x * xv[t][1].x + w1.y * xv[t][1].y + w1.z * xv[t][1].z + w1.w * xv[t][1].w +
                w2.x * xv[t][2].x + w2.y * xv[t][2].y + w2.z * xv[t][2].z + w2.w * xv[t][2].w +
                w3.x * xv[t][3].x + w3.y * xv[t][3].y + w3.z * xv[t][3].z + w3.w * xv[t][3].w;
    }
  }
  // spill partials to LDS, rotation-swizzled so reduce reads are bank-spread
#pragma unroll
  for (int t = 0; t < 4; ++t)
#pragma unroll
    for (int e = 0; e < 8; ++e) {
      int j = (wv * 4 + t) * 8 + e;
      part[j * 64 + ((lane + 4 * j) & 63)] = p[t][e];
    }
  __syncthreads();

  // reduce: 128 jobs (16 tok x 8 e), each sums 64 partials via 16 b128 reads
  if (tid < 128) {
    float s = 0.f;
#pragma unroll
    for (int m = 0; m < 16; ++m) {
      int kk = (4 * m + 4 * tid) & 63;
      float4 v = *(const float4*)&part[tid * 64 + kk];
      s += v.x + v.y + v.z + v.w;
    }
    lgs[tid] = s;
  }
  __syncthreads();

  // softmax + top2, one thread per token
  if (tid < 16) {
    float lg[8];
#pragma unroll
    for (int e = 0; e < 8; ++e) lg[e] = lgs[tid * 8 + e];
    int i1 = 0; float m1 = lg[0];
#pragma unroll
    for (int e = 1; e < 8; ++e) { if (lg[e] > m1) { m1 = lg[e]; i1 = e; } }
    int i2 = -1; float m2 = -3.4e38f;
#pragma unroll
    for (int e = 0; e < 8; ++e) { if (e != i1 && lg[e] > m2) { m2 = lg[e]; i2 = e; } }
    float Z = 0.f;
#pragma unroll
    for (int e = 0; e < 8; ++e) Z += expf(lg[e] - m1);
    float s1 = 1.f / Z;
    float s2 = expf(m2 - m1) / Z;
    float dn = s1 + s2 + 1e-20f;
    float w1 = s1 / dn, w2 = s2 / dn;
    int ef, es; float wf, wsx;
    if (i1 < i2) { ef = i1; es = i2; wf = w1; wsx = w2; }
    else         { ef = i2; es = i1; wf = w2; wsx = w1; }
    int pq = ef * 7 - (ef * (ef - 1)) / 2 + (es - ef - 1);   // C(8,2) index, ef<es
    int t = g * 16 + tid;
    wpair[t] = make_float2(wf, wsx);
    pid[t] = pq;
  }
}

// ---------------- K2: atomic-free routing: histogram + prefix + rank assignment ----------------
__global__ __launch_bounds__(256) void route_scan(const int* __restrict__ pid,
                                                  int* __restrict__ perm,
                                                  int4* __restrict__ tiletab,
                                                  int* __restrict__ ntct) {
  __shared__ int hist[256 * 29];
  __shared__ int totals[NPAIR];
  __shared__ int spre[256];
  const int p   = blockIdx.x;
  const int tid = threadIdx.x;
#pragma unroll
  for (int q = 0; q < 29; ++q) hist[tid * 29 + q] = 0;
  __syncthreads();
  for (int k = 0; k < 64; ++k) {
    int q = pid[tid + (k << 8)];
    hist[tid * 29 + q]++;
  }
  __syncthreads();
  if (tid < NPAIR) {
    int s = 0;
    for (int i = 0; i < 256; ++i) s += hist[i * 29 + tid];
    totals[tid] = s;
  }
  __syncthreads();
  const int mycnt = hist[tid * 29 + p];
  spre[tid] = mycnt;
  __syncthreads();
  for (int d = 1; d < 256; d <<= 1) {
    int add = (tid >= d) ? spre[tid - d] : 0;
    __syncthreads();
    spre[tid] += add;
    __syncthreads();
  }
  int estart = 0, tstart = 0;
  for (int q = 0; q < p; ++q) { estart += totals[q]; tstart += (totals[q] + 127) >> 7; }
  const int cp = totals[p];
  const int nt = (cp + 127) >> 7;
  if (p == NPAIR - 1 && tid == 0) ntct[0] = tstart + nt;
  for (int k = tid; k < nt; k += 256) {
    int4 e;
    e.x = p;
    e.y = estart + (k << 7);
    e.z = min(128, cp - (k << 7));
    e.w = (tstart + k) << 7;
    tiletab[tstart + k] = e;
  }
  int wr = estart + spre[tid] - mycnt;
  for (int k = 0; k < 64; ++k) {
    int t = tid + (k << 8);
    if (pid[t] == p) perm[wr++] = t;
  }
}

// ---------------- G1: grouped fc1: gather x rows, [128x768] per pair-tile ----------------
__global__ __launch_bounds__(256) void moe_fc1(const unsigned short* __restrict__ xbf,
                                               const unsigned short* __restrict__ W1cat,
                                               const int* __restrict__ perm,
                                               const float2* __restrict__ wpair,
                                               const float* __restrict__ bias1,
                                               const int4* __restrict__ tiletab,
                                               const int* __restrict__ ntct,
                                               unsigned short* __restrict__ Hbuf) {
  const int L   = blockIdx.x;
  const int xcd = L & 7;
  const int s   = L >> 3;
  const int mg  = s / 6;
  const int nn  = s - mg * 6;
  const int mt  = xcd + (mg << 3);
  if (mt >= ntct[0]) return;
  const int4 tt = tiletab[mt];
  const int eoff = tt.y, valid = tt.z, hbase = tt.w;
  int ef = 0, rem = tt.x;
  while (rem >= 7 - ef) { rem -= 7 - ef; ef++; }
  const int es = ef + 1 + rem;
  const int brow = (nn == 0) ? ef * 128 : (nn == 1) ? es * 128 : 1024 + ((nn - 2) << 7);

  __shared__ __align__(16) unsigned short As[128 * 64];
  __shared__ __align__(16) unsigned short Bs[128 * 64];

  const int tid  = threadIdx.x;
  const int lane = tid & 63;
  const int wv   = tid >> 6;
  const int wm   = wv >> 1;
  const int wn   = wv & 1;
  const int r16  = lane & 15;
  const int quad = lane >> 4;

  const unsigned short* gA[4];
  const unsigned short* gB[4];
  unsigned short* lA[4];
  unsigned short* lB[4];
#pragma unroll
  for (int i = 0; i < 4; ++i) {
    int idx = i * 256 + tid;
    int row = idx >> 3;
    int cc  = idx & 7;
    int kc  = cc ^ (row & 7);
    int tok = perm[eoff + min(row, valid - 1)];
    gA[i] = xbf + (size_t)tok * HD + kc * 8;
    gB[i] = W1cat + (size_t)(brow + row) * HD + kc * 8;
    lA[i] = As + idx * 8;
    lB[i] = Bs + idx * 8;
  }

  int aoff[4], boff[4];
#pragma unroll
  for (int i = 0; i < 4; ++i) {
    int ra = wm * 64 + i * 16 + r16;
    aoff[i] = ra * 64 + ((quad ^ (ra & 7)) << 3);
    int rb = wn * 64 + i * 16 + r16;
    boff[i] = rb * 64 + ((quad ^ (rb & 7)) << 3);
  }

  f32x4 acc[4][4];
#pragma unroll
  for (int i = 0; i < 4; ++i)
#pragma unroll
    for (int j = 0; j < 4; ++j) acc[i][j] = (f32x4){0.f, 0.f, 0.f, 0.f};

  for (int kt = 0; kt < 16; ++kt) {
    const int ko = kt << 6;
#pragma unroll
    for (int i = 0; i < 4; ++i) gl2lds16(gA[i] + ko, lA[i]);
#pragma unroll
    for (int i = 0; i < 4; ++i) gl2lds16(gB[i] + ko, lB[i]);
    __syncthreads();
#pragma unroll
    for (int g = 0; g < 2; ++g) {
      const int gx = g << 5;
      bf16x8 av[4], bv[4];
#pragma unroll
      for (int i = 0; i < 4; ++i) av[i] = *(const bf16x8*)(As + (aoff[i] ^ gx));
#pragma unroll
      for (int j = 0; j < 4; ++j) bv[j] = *(const bf16x8*)(Bs + (boff[j] ^ gx));
#pragma unroll
      for (int i = 0; i < 4; ++i)
#pragma unroll
        for (int j = 0; j < 4; ++j)
          acc[i][j] = __builtin_amdgcn_mfma_f32_16x16x32_bf16(av[i], bv[j], acc[i][j], 0, 0, 0);
    }
    __syncthreads();
  }

  // epilogue: relu(acc+b)*scale, scale = w1/w2/1 by nn
  float* wl = (float*)As;
  if (tid < 128) {
    int tok = perm[eoff + min(tid, valid - 1)];
    float sc = 1.0f;
    if (nn == 0) sc = wpair[tok].x;
    else if (nn == 1) sc = wpair[tok].y;
    wl[tid] = sc;
  }
  __syncthreads();
#pragma unroll
  for (int j = 0; j < 4; ++j) {
    const int cin = wn * 64 + j * 16 + r16;
    const float bz = bias1[brow + cin];
#pragma unroll
    for (int i = 0; i < 4; ++i) {
#pragma unroll
      for (int r = 0; r < 4; ++r) {
        const int lrow = wm * 64 + i * 16 + quad * 4 + r;
        float v = fmaxf(acc[i][j][r] + bz, 0.f) * wl[lrow];
        Hbuf[(size_t)(hbase + lrow) * NH + nn * 128 + cin] = f2bf(v);
      }
    }
  }
}

// ---------------- G2: grouped fc2: [128 tokens] x [128 h-cols], K=768, scatter out ----------------
__global__ __launch_bounds__(256) void moe_fc2(const unsigned short* __restrict__ Hbuf,
                                               const unsigned short* __restrict__ W2cat,
                                               const int* __restrict__ perm,
                                               const float2* __restrict__ wpair,
                                               const float* __restrict__ b2,
                                               const float* __restrict__ bs2,
                                               const int4* __restrict__ tiletab,
                                               const int* __restrict__ ntct,
                                               float* __restrict__ out) {
  const int L   = blockIdx.x;
  const int xcd = L & 7;
  const int s   = L >> 3;
  const int mg  = s >> 3;
  const int nn  = s & 7;
  const int mt  = xcd + (mg << 3);
  if (mt >= ntct[0]) return;
  const int4 tt = tiletab[mt];
  const int eoff = tt.y, valid = tt.z, hbase = tt.w;
  int ef = 0, rem = tt.x;
  while (rem >= 7 - ef) { rem -= 7 - ef; ef++; }
  const int es = ef + 1 + rem;
  const int tileN = nn << 7;

  __shared__ __align__(16) unsigned short As[128 * 64];
  __shared__ __align__(16) unsigned short Bs[128 * 64];

  const int tid  = threadIdx.x;
  const int lane = tid & 63;
  const int wv   = tid >> 6;
  const int wm   = wv >> 1;
  const int wn   = wv & 1;
  const int r16  = lane & 15;
  const int quad = lane >> 4;

  const unsigned short* gA[4];
  const unsigned short* gB[4];
  unsigned short* lA[4];
  unsigned short* lB[4];
#pragma unroll
  for (int i = 0; i < 4; ++i) {
    int idx = i * 256 + tid;
    int row = idx >> 3;
    int cc  = idx & 7;
    int kc  = cc ^ (row & 7);
    gA[i] = Hbuf + (size_t)(hbase + row) * NH + kc * 8;
    gB[i] = W2cat + (size_t)(tileN + row) * KC2 + kc * 8;
    lA[i] = As + idx * 8;
    lB[i] = Bs + idx * 8;
  }

  int aoff[4], boff[4];
#pragma unroll
  for (int i = 0; i < 4; ++i) {
    int ra = wm * 64 + i * 16 + r16;
    aoff[i] = ra * 64 + ((quad ^ (ra & 7)) << 3);
    int rb = wn * 64 + i * 16 + r16;
    boff[i] = rb * 64 + ((quad ^ (rb & 7)) << 3);
  }

  f32x4 acc[4][4];
#pragma unroll
  for (int i = 0; i < 4; ++i)
#pragma unroll
    for (int j = 0; j < 4; ++j) acc[i][j] = (f32x4){0.f, 0.f, 0.f, 0.f};

  for (int kt = 0; kt < 12; ++kt) {
    const int koA = kt << 6;
    const int koB = (kt < 2) ? ef * 128 + (kt << 6)
                 : (kt < 4) ? es * 128 + ((kt - 2) << 6)
                            : 1024 + ((kt - 4) << 6);
#pragma unroll
    for (int i = 0; i < 4; ++i) gl2lds16(gA[i] + koA, lA[i]);
#pragma unroll
    for (int i = 0; i < 4; ++i) gl2lds16(gB[i] + koB, lB[i]);
    __syncthreads();
#pragma unroll
    for (int g = 0; g < 2; ++g) {
      const int gx = g << 5;
      bf16x8 av[4], bv[4];
#pragma unroll
      for (int i = 0; i < 4; ++i) av[i] = *(const bf16x8*)(As + (aoff[i] ^ gx));
#pragma unroll
      for (int j = 0; j < 4; ++j) bv[j] = *(const bf16x8*)(Bs + (boff[j] ^ gx));
#pragma unroll
      for (int i = 0; i < 4; ++i)
#pragma unroll
        for (int j = 0; j < 4; ++j)
          acc[i][j] = __builtin_amdgcn_mfma_f32_16x16x32_bf16(av[i], bv[j], acc[i][j], 0, 0, 0);
    }
    __syncthreads();
  }

  // epilogue: + bs2 + w1*b2[e1] + w2*b2[e2], scatter to out[token]
  float2* wl2 = (float2*)As;
  int* tokl   = (int*)Bs;
  if (tid < 128) {
    int tokc = perm[eoff + min(tid, valid - 1)];
    tokl[tid] = (tid < valid) ? tokc : -1;
    wl2[tid] = wpair[tokc];
  }
  __syncthreads();
  float bsc[4], b2a[4], b2b[4];
#pragma unroll
  for (int j = 0; j < 4; ++j) {
    const int col = tileN + wn * 64 + j * 16 + r16;
    bsc[j] = bs2[col];
    b2a[j] = b2[(size_t)ef * HD + col];
    b2b[j] = b2[(size_t)es * HD + col];
  }
#pragma unroll
  for (int i = 0; i < 4; ++i) {
#pragma unroll
    for (int r = 0; r < 4; ++r) {
      const int lrow = wm * 64 + i * 16 + quad * 4 + r;
      const int tok = tokl[lrow];
      if (tok < 0) continue;
      const float2 w = wl2[lrow];
#pragma unroll
      for (int j = 0; j < 4; ++j) {
        const int col = tileN + wn * 64 + j * 16 + r16;
        out[(size_t)tok * HD + col] = acc[i][j][r] + bsc[j] + w.x * b2a[j] + w.y * b2b[j];
      }
    }
  }
}

extern "C" void kernel_launch(void* const* d_in, const int* in_sizes, int n_in,
                              void* d_out, int out_size, void* d_ws, size_t ws_size,
                              hipStream_t stream) {
  const float* x   = (const float*)d_in[0];
  const float* Wg  = (const float*)d_in[1];
  const float* W1  = (const float*)d_in[2];
  const float* b1  = (const float*)d_in[3];
  const float* W2  = (const float*)d_in[4];
  const float* b2  = (const float*)d_in[5];
  const float* Ws1 = (const float*)d_in[6];
  const float* bs1 = (const float*)d_in[7];
  const float* Ws2 = (const float*)d_in[8];
  const float* bs2 = (const float*)d_in[9];

  char* ws = (char*)d_ws;
  size_t off = 0;
  unsigned short* xbf   = (unsigned short*)(ws + off); off += (size_t)TTOK * HD * 2;       // 32 MiB
  unsigned short* Hbuf  = (unsigned short*)(ws + off); off += (size_t)MAXT * 128 * NH * 2; // 30 MiB
  unsigned short* W1cat = (unsigned short*)(ws + off); off += (size_t)NC1 * HD * 2;
  unsigned short* W2cat = (unsigned short*)(ws + off); off += (size_t)HD * KC2 * 2;
  float* bias1          = (float*)(ws + off);          off += (size_t)NC1 * 4;
  float2* wpair         = (float2*)(ws + off);         off += (size_t)TTOK * 8;
  int* pid              = (int*)(ws + off);            off += (size_t)TTOK * 4;
  int* perm             = (int*)(ws + off);            off += (size_t)TTOK * 4;
  int4* tiletab         = (int4*)(ws + off);           off += (size_t)MAXT * 16;
  int* ntct             = (int*)(ws + off);            off += 16;

  prep_gate<<<PREPB + GATEB, 256, 0, stream>>>(x, Wg, W1, Ws1, W2, Ws2, b1, bs1,
                                               W1cat, W2cat, bias1, xbf, wpair, pid);
  route_scan<<<NPAIR, 256, 0, stream>>>(pid, perm, tiletab, ntct);
  moe_fc1<<<8 * 20 * 6, 256, 0, stream>>>(xbf, W1cat, perm, wpair, bias1, tiletab, ntct, Hbuf);
  moe_fc2<<<8 * 20 * 8, 256, 0, stream>>>(Hbuf, W2cat, perm, wpair, b2, bs2, tiletab, ntct,
                                          (float*)d_out);
}